// Round 2
// baseline (488.844 us; speedup 1.0000x reference)
//
#include <hip/hip_runtime.h>
#include <math.h>

#define EPSF 1e-7f

__device__ __forceinline__ float wave_reduce_sum(float v) {
    #pragma unroll
    for (int o = 32; o > 0; o >>= 1) v += __shfl_xor(v, o, 64);
    return v;
}

__device__ __forceinline__ unsigned short f2bf(float f) {
    unsigned u = __float_as_uint(f);
    u = (u + 0x7fffu + ((u >> 16) & 1u)) >> 16;
    return (unsigned short)u;
}
__device__ __forceinline__ float bf2f(unsigned short s) {
    return __uint_as_float(((unsigned)s) << 16);
}

// K1: x_tan = logmap0(x_hyp, c_sphere). One block per row.
__global__ void k_logmap(const float* __restrict__ x, const float* __restrict__ c_sphere,
                         float* __restrict__ x_tan, int N, int D) {
    int row = blockIdx.x;
    const float* xr = x + (size_t)row * D;
    float* outr = x_tan + (size_t)row * D;
    float c = c_sphere[0];
    float sqc = fmaxf(sqrtf(c), EPSF);
    float ss = 0.f;
    for (int i = threadIdx.x; i < D; i += blockDim.x) { float v = xr[i]; ss += v * v; }
    __shared__ float red[4];
    ss = wave_reduce_sum(ss);
    int lane = threadIdx.x & 63, wave = threadIdx.x >> 6;
    if (lane == 0) red[wave] = ss;
    __syncthreads();
    ss = red[0] + red[1] + red[2] + red[3];
    float yn = sqrtf(ss);
    float scale;
    if (yn < EPSF) scale = 0.f;
    else scale = atanhf(fminf(yn, 1.f - EPSF)) / sqc / fmaxf(yn, EPSF);
    for (int i = threadIdx.x; i < D; i += blockDim.x) outr[i] = xr[i] * scale;
}

// Generic fp32 tiled GEMM: C[M,N] = A[M,K] @ B[K,N] + bias[N]
// 64x64 tile, BK=16, 256 threads, 4x4 micro-tile. Pad 68 -> 16B-aligned b128 reads.
__global__ void k_gemm_bias(const float* __restrict__ A, const float* __restrict__ B,
                            const float* __restrict__ bias, float* __restrict__ C,
                            int M, int N, int K) {
    __shared__ __align__(16) float As[16][68];
    __shared__ __align__(16) float Bs[16][68];
    int tid = threadIdx.x;
    int tx = tid & 15, ty = tid >> 4;
    int row0 = blockIdx.y * 64, col0 = blockIdx.x * 64;
    float acc[4][4] = {};
    for (int k0 = 0; k0 < K; k0 += 16) {
        #pragma unroll
        for (int r = 0; r < 4; ++r) {
            int e = tid + r * 256;
            int m = e >> 4, kk = e & 15;
            As[kk][m] = A[(size_t)(row0 + m) * K + k0 + kk];
        }
        #pragma unroll
        for (int r = 0; r < 4; ++r) {
            int e = tid + r * 256;
            int kk = e >> 6, n = e & 63;
            Bs[kk][n] = B[(size_t)(k0 + kk) * N + col0 + n];
        }
        __syncthreads();
        #pragma unroll
        for (int kk = 0; kk < 16; ++kk) {
            float4 a = *reinterpret_cast<const float4*>(&As[kk][ty * 4]);
            float4 b = *reinterpret_cast<const float4*>(&Bs[kk][tx * 4]);
            float aa[4] = {a.x, a.y, a.z, a.w};
            float bb[4] = {b.x, b.y, b.z, b.w};
            #pragma unroll
            for (int i = 0; i < 4; ++i)
                #pragma unroll
                for (int j = 0; j < 4; ++j)
                    acc[i][j] += aa[i] * bb[j];
        }
        __syncthreads();
    }
    #pragma unroll
    for (int i = 0; i < 4; ++i) {
        int r = row0 + ty * 4 + i;
        #pragma unroll
        for (int j = 0; j < 4; ++j) {
            int cidx = col0 + tx * 4 + j;
            C[(size_t)r * N + cidx] = acc[i][j] + bias[cidx];
        }
    }
}

// K3: RoPE on q,k; expmap0; relayout v. One wave per (h,n) vector.
__global__ void k_rope_expmap(const float* __restrict__ qkv, const float* __restrict__ freqs,
                              const float* __restrict__ c_logits,
                              float* __restrict__ qh, float* __restrict__ kh,
                              float* __restrict__ vout,
                              float* __restrict__ x2q, float* __restrict__ y2k) {
    const int N = 512;
    int wave = threadIdx.x >> 6, lane = threadIdx.x & 63;
    int vec = blockIdx.x * 4 + wave;     // vec = h*N + n
    int h = vec >> 9;
    int n = vec & 511;
    float c = log1pf(expf(c_logits[h]));
    float sqc = fmaxf(sqrtf(c), EPSF);
    int j = lane & 31;
    float f = freqs[n * 32 + j];
    float cs = cosf(f), sn = sinf(f);
    const float* base = qkv + (size_t)n * 1536;
    size_t oidx = ((size_t)h * N + n) * 64 + lane;

    {
        float qa = base[h * 64 + lane];
        float qb = base[h * 64 + (lane ^ 32)];
        float qr = (lane < 32) ? (qa * cs - qb * sn) : (qa * cs + qb * sn);
        float vn2 = wave_reduce_sum(qr * qr);
        float vn = sqrtf(vn2);
        float scale, fn;
        if (vn < EPSF) { scale = 0.f; fn = 0.f; }
        else {
            float mag = tanhf(sqc * vn) / sqc;
            scale = mag / fmaxf(vn, EPSF);
            fn = mag;
            if (fn >= 1.f) { scale *= (1.f - EPSF) / fn; fn = 1.f - EPSF; }
        }
        qh[oidx] = qr * scale;
        if (lane == 0) x2q[h * N + n] = fn * fn;
    }
    {
        float ka = base[512 + h * 64 + lane];
        float kb = base[512 + h * 64 + (lane ^ 32)];
        float kr = (lane < 32) ? (ka * cs - kb * sn) : (ka * cs + kb * sn);
        float vn2 = wave_reduce_sum(kr * kr);
        float vn = sqrtf(vn2);
        float scale, fn;
        if (vn < EPSF) { scale = 0.f; fn = 0.f; }
        else {
            float mag = tanhf(sqc * vn) / sqc;
            scale = mag / fmaxf(vn, EPSF);
            fn = mag;
            if (fn >= 1.f) { scale *= (1.f - EPSF) / fn; fn = 1.f - EPSF; }
        }
        kh[oidx] = kr * scale;
        if (lane == 0) y2k[h * N + n] = fn * fn;
    }
    vout[oidx] = base[1024 + h * 64 + lane];
}

// K4a: S-tile = Q K^T per lower-triangular (h, qt, kt) 64x64 tile; epilogue:
// hyperbolic dist transform + causal mask + exp -> P (bf16). No max needed
// (scores <= 0 since dist >= 0 and geo_scale >= 0).
__global__ void k_qkt(const float* __restrict__ qh, const float* __restrict__ kh,
                      const float* __restrict__ x2q, const float* __restrict__ y2k,
                      const float* __restrict__ c_logits, const float* __restrict__ geo_scale,
                      unsigned short* __restrict__ P) {
    const int N = 512;
    int p = blockIdx.x;           // 0..35 lower-triangular tile pairs
    int h = blockIdx.y;
    int qt = (int)((sqrtf(8.f * p + 1.f) - 1.f) * 0.5f);
    while ((qt + 1) * (qt + 2) / 2 <= p) qt++;
    while (qt * (qt + 1) / 2 > p) qt--;
    int kt = p - qt * (qt + 1) / 2;

    __shared__ __align__(16) float Qs[64][68];   // [d][row]
    __shared__ __align__(16) float Ks[64][68];   // [d][row]
    int tid = threadIdx.x;
    int tx = tid & 15, ty = tid >> 4;
    {
        int d = tid & 63;
        int rbase = tid >> 6;
        const float* qb = qh + (((size_t)h * N + qt * 64) * 64);
        const float* kb = kh + (((size_t)h * N + kt * 64) * 64);
        #pragma unroll
        for (int r = 0; r < 16; ++r) {
            int row = r * 4 + rbase;
            Qs[d][row] = qb[(size_t)row * 64 + d];
            Ks[d][row] = kb[(size_t)row * 64 + d];
        }
    }
    __syncthreads();
    float acc[4][4] = {};
    #pragma unroll
    for (int d = 0; d < 64; ++d) {
        float4 a = *reinterpret_cast<const float4*>(&Qs[d][ty * 4]);
        float4 b = *reinterpret_cast<const float4*>(&Ks[d][tx * 4]);
        float aa[4] = {a.x, a.y, a.z, a.w};
        float bb[4] = {b.x, b.y, b.z, b.w};
        #pragma unroll
        for (int i = 0; i < 4; ++i)
            #pragma unroll
            for (int j = 0; j < 4; ++j)
                acc[i][j] += aa[i] * bb[j];
    }
    // epilogue: dist + mask + exp -> bf16 P
    float c = log1pf(expf(c_logits[h]));
    float sqc = fmaxf(sqrtf(c), EPSF);
    float gs = geo_scale[h];
    float x2v[4], bv[4], y2v[4];
    int qiv[4], kiv[4];
    #pragma unroll
    for (int i = 0; i < 4; ++i) {
        qiv[i] = qt * 64 + ty * 4 + i;
        x2v[i] = x2q[h * N + qiv[i]];
        bv[i] = 1.f - c * x2v[i];
    }
    #pragma unroll
    for (int j = 0; j < 4; ++j) {
        kiv[j] = kt * 64 + tx * 4 + j;
        y2v[j] = y2k[h * N + kiv[j]];
    }
    #pragma unroll
    for (int i = 0; i < 4; ++i) {
        unsigned short pv4[4];
        #pragma unroll
        for (int j = 0; j < 4; ++j) {
            float dot = acc[i][j];
            float x2 = x2v[i], y2 = y2v[j], b_ = bv[i];
            float a_ = 1.f + c * (y2 - 2.f * dot);
            float num2 = a_ * a_ * x2 + b_ * b_ * y2 - 2.f * a_ * b_ * dot;
            float den = fmaxf(1.f - 2.f * c * dot + c * c * x2 * y2, EPSF);
            float nrm = sqrtf(fmaxf(num2, 0.f)) / den;
            if (nrm >= 1.f) nrm = 1.f - EPSF;
            float arg = fminf(sqc * nrm, 1.f - EPSF);
            float s = -gs * (2.f * atanhf(arg) / sqc);
            float pe = (kiv[j] <= qiv[i]) ? expf(s) : 0.f;
            pv4[j] = f2bf(pe);
        }
        unsigned short* prow = P + ((size_t)(h * N + qiv[i])) * N + kt * 64 + tx * 4;
        *reinterpret_cast<ushort4*>(prow) = make_ushort4(pv4[0], pv4[1], pv4[2], pv4[3]);
    }
}

// K4b: inv_l[row] = 1 / sum(P[row, 0..written_range)). One wave per row.
__global__ void k_rowsum(const unsigned short* __restrict__ P, float* __restrict__ inv_l) {
    const int N = 512;
    int lane = threadIdx.x & 63, wave = threadIdx.x >> 6;
    int row = blockIdx.x * 4 + wave;          // row = h*N + qi, 0..4095
    int qi = row & (N - 1);
    int kend = ((qi >> 6) + 1) << 6;          // only causal tiles were written
    const unsigned short* pr = P + (size_t)row * N;
    float s = 0.f;
    for (int ki = lane; ki < kend; ki += 64) s += bf2f(pr[ki]);
    s = wave_reduce_sum(s);
    if (lane == 0) inv_l[row] = 1.f / s;
}

// K4c: O(32x64 tile) = P @ V, scaled by inv_l. Grid (16 qtiles, 8 heads).
__global__ void k_pv(const unsigned short* __restrict__ P, const float* __restrict__ v,
                     const float* __restrict__ inv_l, float* __restrict__ aout) {
    const int N = 512;
    int qt = blockIdx.x;          // 32-row tiles
    int h = blockIdx.y;
    int r0 = qt * 32;
    int kmax = (qt / 2 + 1) * 64;
    __shared__ float Ps[64][33];                  // [kk][row]
    __shared__ __align__(16) float Vs[64][68];    // [kk][d]
    int tid = threadIdx.x;
    int tx = tid & 15, ty = tid >> 4;
    float acc[2][4] = {};
    for (int k0 = 0; k0 < kmax; k0 += 64) {
        // stage P (transpose, bf16->f32): 32 rows x 64 kk
        {
            int i0 = tid >> 5;                    // 8 rows per pass
            int kk0 = (tid & 31) * 2;
            #pragma unroll
            for (int p4 = 0; p4 < 4; ++p4) {
                int i = p4 * 8 + i0;
                unsigned u = *reinterpret_cast<const unsigned*>(
                    &P[((size_t)(h * N + r0 + i)) * N + k0 + kk0]);
                Ps[kk0][i] = bf2f((unsigned short)(u & 0xffffu));
                Ps[kk0 + 1][i] = bf2f((unsigned short)(u >> 16));
            }
        }
        // stage V: 64 rows x 64 d
        {
            int d = tid & 63;
            int rbase = tid >> 6;
            #pragma unroll
            for (int r = 0; r < 16; ++r) {
                int row = r * 4 + rbase;
                Vs[row][d] = v[((size_t)h * N + k0 + row) * 64 + d];
            }
        }
        __syncthreads();
        #pragma unroll
        for (int kk = 0; kk < 64; ++kk) {
            float a0 = Ps[kk][ty * 2];
            float a1 = Ps[kk][ty * 2 + 1];
            float4 b = *reinterpret_cast<const float4*>(&Vs[kk][tx * 4]);
            float bb[4] = {b.x, b.y, b.z, b.w};
            #pragma unroll
            for (int j = 0; j < 4; ++j) {
                acc[0][j] += a0 * bb[j];
                acc[1][j] += a1 * bb[j];
            }
        }
        __syncthreads();
    }
    #pragma unroll
    for (int i2 = 0; i2 < 2; ++i2) {
        int qi = r0 + ty * 2 + i2;
        float il = inv_l[h * N + qi];
        float4 o = make_float4(acc[i2][0] * il, acc[i2][1] * il, acc[i2][2] * il, acc[i2][3] * il);
        *reinterpret_cast<float4*>(&aout[(size_t)qi * 512 + h * 64 + tx * 4]) = o;
    }
}

extern "C" void kernel_launch(void* const* d_in, const int* in_sizes, int n_in,
                              void* d_out, int out_size, void* d_ws, size_t ws_size,
                              hipStream_t stream) {
    const float* x_hyp     = (const float*)d_in[0];
    const float* freqs     = (const float*)d_in[1];
    const float* c_sphere  = (const float*)d_in[2];
    const float* w_qkv     = (const float*)d_in[3];
    const float* b_qkv     = (const float*)d_in[4];
    const float* w_out     = (const float*)d_in[5];
    const float* b_out     = (const float*)d_in[6];
    const float* c_logits  = (const float*)d_in[7];
    const float* geo_scale = (const float*)d_in[8];
    float* out = (float*)d_out;
    float* ws  = (float*)d_ws;

    const int N = 512, D = 512, H = 8;
    float* x_tan = ws;                       // 512*512
    float* qkv   = x_tan + N * D;            // 512*1536
    float* qh    = qkv + N * 1536;           // 8*512*64
    float* kh2   = qh + H * N * 64;          // 8*512*64
    float* vv    = kh2 + H * N * 64;         // 8*512*64
    float* x2q   = vv + H * N * 64;          // 8*512
    float* y2k   = x2q + H * N;              // 8*512
    float* aout  = y2k + H * N;              // 512*512
    float* inv_l = aout + N * D;             // 8*512
    unsigned short* P = (unsigned short*)(inv_l + H * N);  // 8*512*512 bf16

    k_logmap<<<N, 256, 0, stream>>>(x_hyp, c_sphere, x_tan, N, D);
    k_gemm_bias<<<dim3(1536 / 64, N / 64), 256, 0, stream>>>(x_tan, w_qkv, b_qkv, qkv, N, 1536, D);
    k_rope_expmap<<<(H * N) / 4, 256, 0, stream>>>(qkv, freqs, c_logits, qh, kh2, vv, x2q, y2k);
    k_qkt<<<dim3(36, H), 256, 0, stream>>>(qh, kh2, x2q, y2k, c_logits, geo_scale, P);
    k_rowsum<<<(H * N) / 4, 256, 0, stream>>>(P, inv_l);
    k_pv<<<dim3(16, H), 256, 0, stream>>>(P, vv, inv_l, aout);
    k_gemm_bias<<<dim3(D / 64, N / 64), 256, 0, stream>>>(aout, w_out, b_out, out, N, D, D);
}

// Round 3
// 117.695 us; speedup vs baseline: 4.1535x; 4.1535x over previous
//
#include <hip/hip_runtime.h>
#include <math.h>

#define EPSF 1e-7f

__device__ __forceinline__ float wave_reduce_sum(float v) {
    #pragma unroll
    for (int o = 32; o > 0; o >>= 1) v += __shfl_xor(v, o, 64);
    return v;
}

__device__ __forceinline__ unsigned short f2bf(float f) {
    unsigned u = __float_as_uint(f);
    u = (u + 0x7fffu + ((u >> 16) & 1u)) >> 16;
    return (unsigned short)u;
}
__device__ __forceinline__ float bf2f(unsigned short s) {
    return __uint_as_float(((unsigned)s) << 16);
}

// K1: x_tan = logmap0(x_hyp, c_sphere). One block per row.
__global__ void k_logmap(const float* __restrict__ x, const float* __restrict__ c_sphere,
                         float* __restrict__ x_tan, int N, int D) {
    int row = blockIdx.x;
    const float* xr = x + (size_t)row * D;
    float* outr = x_tan + (size_t)row * D;
    float c = c_sphere[0];
    float sqc = fmaxf(sqrtf(c), EPSF);
    float ss = 0.f;
    for (int i = threadIdx.x; i < D; i += blockDim.x) { float v = xr[i]; ss += v * v; }
    __shared__ float red[4];
    ss = wave_reduce_sum(ss);
    int lane = threadIdx.x & 63, wave = threadIdx.x >> 6;
    if (lane == 0) red[wave] = ss;
    __syncthreads();
    ss = red[0] + red[1] + red[2] + red[3];
    float yn = sqrtf(ss);
    float scale;
    if (yn < EPSF) scale = 0.f;
    else scale = atanhf(fminf(yn, 1.f - EPSF)) / sqc / fmaxf(yn, EPSF);
    for (int i = threadIdx.x; i < D; i += blockDim.x) outr[i] = xr[i] * scale;
}

// Generic fp32 tiled GEMM: C[M,N] = A[M,K] @ B[K,N] + bias[N]
// 64x64 tile, BK=16, 256 threads, 4x4 micro-tile.
__global__ __launch_bounds__(256, 4) void k_gemm_bias(
        const float* __restrict__ A, const float* __restrict__ B,
        const float* __restrict__ bias, float* __restrict__ C,
        int M, int N, int K) {
    __shared__ __align__(16) float As[16][68];
    __shared__ __align__(16) float Bs[16][68];
    int tid = threadIdx.x;
    int tx = tid & 15, ty = tid >> 4;
    int row0 = blockIdx.y * 64, col0 = blockIdx.x * 64;
    float acc[4][4] = {};
    for (int k0 = 0; k0 < K; k0 += 16) {
        #pragma unroll
        for (int r = 0; r < 4; ++r) {
            int e = tid + r * 256;
            int m = e >> 4, kk = e & 15;
            As[kk][m] = A[(size_t)(row0 + m) * K + k0 + kk];
        }
        #pragma unroll
        for (int r = 0; r < 4; ++r) {
            int e = tid + r * 256;
            int kk = e >> 6, n = e & 63;
            Bs[kk][n] = B[(size_t)(k0 + kk) * N + col0 + n];
        }
        __syncthreads();
        #pragma unroll
        for (int kk = 0; kk < 16; ++kk) {
            float4 a = *reinterpret_cast<const float4*>(&As[kk][ty * 4]);
            float4 b = *reinterpret_cast<const float4*>(&Bs[kk][tx * 4]);
            float aa[4] = {a.x, a.y, a.z, a.w};
            float bb[4] = {b.x, b.y, b.z, b.w};
            #pragma unroll
            for (int i = 0; i < 4; ++i)
                #pragma unroll
                for (int j = 0; j < 4; ++j)
                    acc[i][j] += aa[i] * bb[j];
        }
        __syncthreads();
    }
    #pragma unroll
    for (int i = 0; i < 4; ++i) {
        int r = row0 + ty * 4 + i;
        #pragma unroll
        for (int j = 0; j < 4; ++j) {
            int cidx = col0 + tx * 4 + j;
            C[(size_t)r * N + cidx] = acc[i][j] + bias[cidx];
        }
    }
}

// K3: RoPE on q,k; expmap0; relayout v. One wave per (h,n) vector.
__global__ void k_rope_expmap(const float* __restrict__ qkv, const float* __restrict__ freqs,
                              const float* __restrict__ c_logits,
                              float* __restrict__ qh, float* __restrict__ kh,
                              float* __restrict__ vout,
                              float* __restrict__ x2q, float* __restrict__ y2k) {
    const int N = 512;
    int wave = threadIdx.x >> 6, lane = threadIdx.x & 63;
    int vec = blockIdx.x * 4 + wave;     // vec = h*N + n
    int h = vec >> 9;
    int n = vec & 511;
    float c = log1pf(expf(c_logits[h]));
    float sqc = fmaxf(sqrtf(c), EPSF);
    int j = lane & 31;
    float f = freqs[n * 32 + j];
    float cs = cosf(f), sn = sinf(f);
    const float* base = qkv + (size_t)n * 1536;
    size_t oidx = ((size_t)h * N + n) * 64 + lane;

    {
        float qa = base[h * 64 + lane];
        float qb = base[h * 64 + (lane ^ 32)];
        float qr = (lane < 32) ? (qa * cs - qb * sn) : (qa * cs + qb * sn);
        float vn2 = wave_reduce_sum(qr * qr);
        float vn = sqrtf(vn2);
        float scale, fn;
        if (vn < EPSF) { scale = 0.f; fn = 0.f; }
        else {
            float mag = tanhf(sqc * vn) / sqc;
            scale = mag / fmaxf(vn, EPSF);
            fn = mag;
            if (fn >= 1.f) { scale *= (1.f - EPSF) / fn; fn = 1.f - EPSF; }
        }
        qh[oidx] = qr * scale;
        if (lane == 0) x2q[h * N + n] = fn * fn;
    }
    {
        float ka = base[512 + h * 64 + lane];
        float kb = base[512 + h * 64 + (lane ^ 32)];
        float kr = (lane < 32) ? (ka * cs - kb * sn) : (ka * cs + kb * sn);
        float vn2 = wave_reduce_sum(kr * kr);
        float vn = sqrtf(vn2);
        float scale, fn;
        if (vn < EPSF) { scale = 0.f; fn = 0.f; }
        else {
            float mag = tanhf(sqc * vn) / sqc;
            scale = mag / fmaxf(vn, EPSF);
            fn = mag;
            if (fn >= 1.f) { scale *= (1.f - EPSF) / fn; fn = 1.f - EPSF; }
        }
        kh[oidx] = kr * scale;
        if (lane == 0) y2k[h * N + n] = fn * fn;
    }
    vout[oidx] = base[1024 + h * 64 + lane];
}

// K4a: S-tile = Q K^T per lower-triangular (h, qt, kt) 64x64 tile; epilogue:
// hyperbolic dist transform + causal mask + exp -> P (bf16).
// Structured EXACTLY like k_gemm_bias (BK=16 chunks) to avoid the R2
// full-unroll register-spill pathology.
__global__ __launch_bounds__(256, 4) void k_qkt(
        const float* __restrict__ qh, const float* __restrict__ kh,
        const float* __restrict__ x2q, const float* __restrict__ y2k,
        const float* __restrict__ c_logits, const float* __restrict__ geo_scale,
        unsigned short* __restrict__ P) {
    const int N = 512;
    int p = blockIdx.x;           // 0..35 lower-triangular tile pairs
    int h = blockIdx.y;
    int qt = 0;
    while ((qt + 1) * (qt + 2) / 2 <= p) qt++;
    int kt = p - qt * (qt + 1) / 2;

    __shared__ __align__(16) float As[16][68];   // [kk][qrow]
    __shared__ __align__(16) float Bs[16][68];   // [kk][krow]
    int tid = threadIdx.x;
    int tx = tid & 15, ty = tid >> 4;
    const float* qb = qh + ((size_t)(h * N + qt * 64)) * 64;
    const float* kb = kh + ((size_t)(h * N + kt * 64)) * 64;
    float acc[4][4] = {};
    for (int k0 = 0; k0 < 64; k0 += 16) {
        #pragma unroll
        for (int r = 0; r < 4; ++r) {
            int e = tid + r * 256;
            int m = e >> 4, kk = e & 15;
            As[kk][m] = qb[(size_t)m * 64 + k0 + kk];
            Bs[kk][m] = kb[(size_t)m * 64 + k0 + kk];
        }
        __syncthreads();
        #pragma unroll
        for (int kk = 0; kk < 16; ++kk) {
            float4 a = *reinterpret_cast<const float4*>(&As[kk][ty * 4]);
            float4 b = *reinterpret_cast<const float4*>(&Bs[kk][tx * 4]);
            float aa[4] = {a.x, a.y, a.z, a.w};
            float bb[4] = {b.x, b.y, b.z, b.w};
            #pragma unroll
            for (int i = 0; i < 4; ++i)
                #pragma unroll
                for (int j = 0; j < 4; ++j)
                    acc[i][j] += aa[i] * bb[j];
        }
        __syncthreads();
    }
    // epilogue: dist + mask + exp -> bf16 P
    float c = log1pf(expf(c_logits[h]));
    float sqc = fmaxf(sqrtf(c), EPSF);
    float gs = geo_scale[h];
    float x2v[4], bv[4], y2v[4];
    int qiv[4], kiv[4];
    #pragma unroll
    for (int i = 0; i < 4; ++i) {
        qiv[i] = qt * 64 + ty * 4 + i;
        x2v[i] = x2q[h * N + qiv[i]];
        bv[i] = 1.f - c * x2v[i];
    }
    #pragma unroll
    for (int j = 0; j < 4; ++j) {
        kiv[j] = kt * 64 + tx * 4 + j;
        y2v[j] = y2k[h * N + kiv[j]];
    }
    #pragma unroll
    for (int i = 0; i < 4; ++i) {
        unsigned short pv4[4];
        #pragma unroll
        for (int j = 0; j < 4; ++j) {
            float dot = acc[i][j];
            float x2 = x2v[i], y2 = y2v[j], b_ = bv[i];
            float a_ = 1.f + c * (y2 - 2.f * dot);
            float num2 = a_ * a_ * x2 + b_ * b_ * y2 - 2.f * a_ * b_ * dot;
            float den = fmaxf(1.f - 2.f * c * dot + c * c * x2 * y2, EPSF);
            float nrm = sqrtf(fmaxf(num2, 0.f)) / den;
            if (nrm >= 1.f) nrm = 1.f - EPSF;
            float arg = fminf(sqc * nrm, 1.f - EPSF);
            float s = -gs * (2.f * atanhf(arg) / sqc);
            float pe = (kiv[j] <= qiv[i]) ? expf(s) : 0.f;
            pv4[j] = f2bf(pe);
        }
        unsigned short* prow = P + ((size_t)(h * N + qiv[i])) * N + kt * 64 + tx * 4;
        *reinterpret_cast<ushort4*>(prow) = make_ushort4(pv4[0], pv4[1], pv4[2], pv4[3]);
    }
}

// K4b: inv_l[row] = 1 / sum(P[row, causal range)). One wave per row.
__global__ void k_rowsum(const unsigned short* __restrict__ P, float* __restrict__ inv_l) {
    const int N = 512;
    int lane = threadIdx.x & 63, wave = threadIdx.x >> 6;
    int row = blockIdx.x * 4 + wave;          // row = h*N + qi, 0..4095
    int qi = row & (N - 1);
    int kend = ((qi >> 6) + 1) << 6;          // only causal tiles were written
    const unsigned short* pr = P + (size_t)row * N;
    float s = 0.f;
    for (int ki = lane; ki < kend; ki += 64) s += bf2f(pr[ki]);
    s = wave_reduce_sum(s);
    if (lane == 0) inv_l[row] = 1.f / s;
}

// K4c: O(32x64 tile) = P @ V, scaled by inv_l. Grid (16 qtiles, 8 heads).
// Inner loop chunked by 16 (same anti-spill discipline).
__global__ __launch_bounds__(256, 4) void k_pv(
        const unsigned short* __restrict__ P, const float* __restrict__ v,
        const float* __restrict__ inv_l, float* __restrict__ aout) {
    const int N = 512;
    int qt = blockIdx.x;          // 32-row tiles
    int h = blockIdx.y;
    int r0 = qt * 32;
    int kmax = (qt / 2 + 1) * 64;
    __shared__ float Ps[64][33];                  // [kk][row]
    __shared__ __align__(16) float Vs[64][68];    // [kk][d]
    int tid = threadIdx.x;
    int tx = tid & 15, ty = tid >> 4;
    float acc[2][4] = {};
    for (int k0 = 0; k0 < kmax; k0 += 64) {
        // stage P (transpose, bf16->f32): 32 rows x 64 kk
        {
            int i0 = tid >> 5;                    // 8 rows per pass
            int kk0 = (tid & 31) * 2;
            #pragma unroll
            for (int p4 = 0; p4 < 4; ++p4) {
                int i = p4 * 8 + i0;
                unsigned u = *reinterpret_cast<const unsigned*>(
                    &P[((size_t)(h * N + r0 + i)) * N + k0 + kk0]);
                Ps[kk0][i] = bf2f((unsigned short)(u & 0xffffu));
                Ps[kk0 + 1][i] = bf2f((unsigned short)(u >> 16));
            }
        }
        // stage V: 64 rows x 64 d
        {
            int d = tid & 63;
            int rbase = tid >> 6;
            #pragma unroll
            for (int r = 0; r < 16; ++r) {
                int row = r * 4 + rbase;
                Vs[row][d] = v[((size_t)h * N + k0 + row) * 64 + d];
            }
        }
        __syncthreads();
        for (int kc = 0; kc < 64; kc += 16) {
            #pragma unroll
            for (int kk2 = 0; kk2 < 16; ++kk2) {
                int kk = kc + kk2;
                float a0 = Ps[kk][ty * 2];
                float a1 = Ps[kk][ty * 2 + 1];
                float4 b = *reinterpret_cast<const float4*>(&Vs[kk][tx * 4]);
                float bb[4] = {b.x, b.y, b.z, b.w};
                #pragma unroll
                for (int j = 0; j < 4; ++j) {
                    acc[0][j] += a0 * bb[j];
                    acc[1][j] += a1 * bb[j];
                }
            }
        }
        __syncthreads();
    }
    #pragma unroll
    for (int i2 = 0; i2 < 2; ++i2) {
        int qi = r0 + ty * 2 + i2;
        float il = inv_l[h * N + qi];
        float4 o = make_float4(acc[i2][0] * il, acc[i2][1] * il, acc[i2][2] * il, acc[i2][3] * il);
        *reinterpret_cast<float4*>(&aout[(size_t)qi * 512 + h * 64 + tx * 4]) = o;
    }
}

extern "C" void kernel_launch(void* const* d_in, const int* in_sizes, int n_in,
                              void* d_out, int out_size, void* d_ws, size_t ws_size,
                              hipStream_t stream) {
    const float* x_hyp     = (const float*)d_in[0];
    const float* freqs     = (const float*)d_in[1];
    const float* c_sphere  = (const float*)d_in[2];
    const float* w_qkv     = (const float*)d_in[3];
    const float* b_qkv     = (const float*)d_in[4];
    const float* w_out     = (const float*)d_in[5];
    const float* b_out     = (const float*)d_in[6];
    const float* c_logits  = (const float*)d_in[7];
    const float* geo_scale = (const float*)d_in[8];
    float* out = (float*)d_out;
    float* ws  = (float*)d_ws;

    const int N = 512, D = 512, H = 8;
    float* x_tan = ws;                       // 512*512
    float* qkv   = x_tan + N * D;            // 512*1536
    float* qh    = qkv + N * 1536;           // 8*512*64
    float* kh2   = qh + H * N * 64;          // 8*512*64
    float* vv    = kh2 + H * N * 64;         // 8*512*64
    float* x2q   = vv + H * N * 64;          // 8*512
    float* y2k   = x2q + H * N;              // 8*512
    float* aout  = y2k + H * N;              // 512*512
    float* inv_l = aout + N * D;             // 8*512
    unsigned short* P = (unsigned short*)(inv_l + H * N);  // 8*512*512 bf16

    k_logmap<<<N, 256, 0, stream>>>(x_hyp, c_sphere, x_tan, N, D);
    k_gemm_bias<<<dim3(1536 / 64, N / 64), 256, 0, stream>>>(x_tan, w_qkv, b_qkv, qkv, N, 1536, D);
    k_rope_expmap<<<(H * N) / 4, 256, 0, stream>>>(qkv, freqs, c_logits, qh, kh2, vv, x2q, y2k);
    k_qkt<<<dim3(36, H), 256, 0, stream>>>(qh, kh2, x2q, y2k, c_logits, geo_scale, P);
    k_rowsum<<<(H * N) / 4, 256, 0, stream>>>(P, inv_l);
    k_pv<<<dim3(16, H), 256, 0, stream>>>(P, vv, inv_l, aout);
    k_gemm_bias<<<dim3(D / 64, N / 64), 256, 0, stream>>>(aout, w_out, b_out, out, N, D, D);
}

// Round 4
// 77.706 us; speedup vs baseline: 6.2909x; 1.5146x over previous
//
#include <hip/hip_runtime.h>
#include <math.h>

#define EPSF 1e-7f

typedef __attribute__((ext_vector_type(4))) float f32x4;
typedef __attribute__((ext_vector_type(8))) short s16x8;

__device__ __forceinline__ float wave_reduce_sum(float v) {
    #pragma unroll
    for (int o = 32; o > 0; o >>= 1) v += __shfl_xor(v, o, 64);
    return v;
}

__device__ __forceinline__ unsigned short f2bf(float f) {
    unsigned u = __float_as_uint(f);
    u = (u + 0x7fffu + ((u >> 16) & 1u)) >> 16;
    return (unsigned short)u;
}
__device__ __forceinline__ float bf2f(unsigned short s) {
    return __uint_as_float(((unsigned)s) << 16);
}

// K1: x_tan(bf16) = logmap0(x_hyp, c_sphere). One block per row.
__global__ void k_logmap(const float* __restrict__ x, const float* __restrict__ c_sphere,
                         unsigned short* __restrict__ x_tan16, int N, int D) {
    int row = blockIdx.x;
    const float* xr = x + (size_t)row * D;
    unsigned short* outr = x_tan16 + (size_t)row * D;
    float c = c_sphere[0];
    float sqc = fmaxf(sqrtf(c), EPSF);
    float ss = 0.f;
    for (int i = threadIdx.x; i < D; i += blockDim.x) { float v = xr[i]; ss += v * v; }
    __shared__ float red[4];
    ss = wave_reduce_sum(ss);
    int lane = threadIdx.x & 63, wave = threadIdx.x >> 6;
    if (lane == 0) red[wave] = ss;
    __syncthreads();
    ss = red[0] + red[1] + red[2] + red[3];
    float yn = sqrtf(ss);
    float scale;
    if (yn < EPSF) scale = 0.f;
    else scale = atanhf(fminf(yn, 1.f - EPSF)) / sqc / fmaxf(yn, EPSF);
    for (int i = threadIdx.x; i < D; i += blockDim.x) outr[i] = f2bf(xr[i] * scale);
}

// K2: transpose fp32 [K][N] -> bf16 [N][K] via 64x64 LDS tile.
__global__ void k_transpose_bf16(const float* __restrict__ in, unsigned short* __restrict__ out,
                                 int K, int N) {
    __shared__ float t[64][65];
    int k0 = blockIdx.y * 64, n0 = blockIdx.x * 64;
    int c = threadIdx.x & 63, r0 = threadIdx.x >> 6;
    #pragma unroll
    for (int i = 0; i < 16; ++i) {
        int r = i * 4 + r0;
        t[r][c] = in[(size_t)(k0 + r) * N + n0 + c];
    }
    __syncthreads();
    #pragma unroll
    for (int i = 0; i < 16; ++i) {
        int r = i * 4 + r0;
        out[(size_t)(n0 + r) * K + k0 + c] = f2bf(t[c][r]);
    }
}

// K3: MFMA GEMM: C(f32)[M][N] = A(bf16)[M][K] @ Bt(bf16)[N][K]^T + bias.
// One wave per 32x32 output tile, frags direct from global, no LDS.
__global__ __launch_bounds__(256, 4) void k_gemm_mfma(
        const unsigned short* __restrict__ A, const unsigned short* __restrict__ Bt,
        const float* __restrict__ bias, float* __restrict__ C,
        int M, int N, int K) {
    int tid = threadIdx.x, lane = tid & 63;
    int wid = blockIdx.x * 4 + (tid >> 6);
    int nwc = N >> 5;
    int wr = wid / nwc, wc = wid - wr * nwc;
    if (wr * 32 >= M) return;
    int l15 = lane & 15, kb = lane >> 4;
    const unsigned short* Ab = A + ((size_t)(wr * 32 + l15)) * K + kb * 8;
    const unsigned short* Bb = Bt + ((size_t)(wc * 32 + l15)) * K + kb * 8;
    f32x4 acc[2][2] = {};
    #pragma unroll 4
    for (int k0 = 0; k0 < K; k0 += 32) {
        s16x8 a0 = *(const s16x8*)(Ab + k0);
        s16x8 a1 = *(const s16x8*)(Ab + (size_t)16 * K + k0);
        s16x8 b0 = *(const s16x8*)(Bb + k0);
        s16x8 b1 = *(const s16x8*)(Bb + (size_t)16 * K + k0);
        acc[0][0] = __builtin_amdgcn_mfma_f32_16x16x32_bf16(a0, b0, acc[0][0], 0, 0, 0);
        acc[0][1] = __builtin_amdgcn_mfma_f32_16x16x32_bf16(a0, b1, acc[0][1], 0, 0, 0);
        acc[1][0] = __builtin_amdgcn_mfma_f32_16x16x32_bf16(a1, b0, acc[1][0], 0, 0, 0);
        acc[1][1] = __builtin_amdgcn_mfma_f32_16x16x32_bf16(a1, b1, acc[1][1], 0, 0, 0);
    }
    #pragma unroll
    for (int mi = 0; mi < 2; ++mi)
        #pragma unroll
        for (int r = 0; r < 4; ++r) {
            int row = wr * 32 + mi * 16 + kb * 4 + r;
            #pragma unroll
            for (int ni = 0; ni < 2; ++ni) {
                int col = wc * 32 + ni * 16 + l15;
                C[(size_t)row * N + col] = acc[mi][ni][r] + bias[col];
            }
        }
}

// K4: RoPE on q,k; expmap0; relayouts. One wave per (h,n) vector.
// Outputs: qh/kh bf16 [H][N][64]; vt bf16 [H][64][N] (transposed for PV);
// squared norms x2q/y2k fp32 [H][N].
__global__ void k_rope_expmap(const float* __restrict__ qkv, const float* __restrict__ freqs,
                              const float* __restrict__ c_logits,
                              unsigned short* __restrict__ qh, unsigned short* __restrict__ kh,
                              unsigned short* __restrict__ vt,
                              float* __restrict__ x2q, float* __restrict__ y2k) {
    const int N = 512;
    int wave = threadIdx.x >> 6, lane = threadIdx.x & 63;
    int vec = blockIdx.x * 4 + wave;     // vec = h*N + n
    int h = vec >> 9;
    int n = vec & 511;
    float c = log1pf(expf(c_logits[h]));
    float sqc = fmaxf(sqrtf(c), EPSF);
    int j = lane & 31;
    float f = freqs[n * 32 + j];
    float cs = cosf(f), sn = sinf(f);
    const float* base = qkv + (size_t)n * 1536;
    size_t oidx = ((size_t)h * N + n) * 64 + lane;

    {
        float qa = base[h * 64 + lane];
        float qb = base[h * 64 + (lane ^ 32)];
        float qr = (lane < 32) ? (qa * cs - qb * sn) : (qa * cs + qb * sn);
        float vn2 = wave_reduce_sum(qr * qr);
        float vn = sqrtf(vn2);
        float scale, fn;
        if (vn < EPSF) { scale = 0.f; fn = 0.f; }
        else {
            float mag = tanhf(sqc * vn) / sqc;
            scale = mag / fmaxf(vn, EPSF);
            fn = mag;
            if (fn >= 1.f) { scale *= (1.f - EPSF) / fn; fn = 1.f - EPSF; }
        }
        qh[oidx] = f2bf(qr * scale);
        if (lane == 0) x2q[h * N + n] = fn * fn;
    }
    {
        float ka = base[512 + h * 64 + lane];
        float kb = base[512 + h * 64 + (lane ^ 32)];
        float kr = (lane < 32) ? (ka * cs - kb * sn) : (ka * cs + kb * sn);
        float vn2 = wave_reduce_sum(kr * kr);
        float vn = sqrtf(vn2);
        float scale, fn;
        if (vn < EPSF) { scale = 0.f; fn = 0.f; }
        else {
            float mag = tanhf(sqc * vn) / sqc;
            scale = mag / fmaxf(vn, EPSF);
            fn = mag;
            if (fn >= 1.f) { scale *= (1.f - EPSF) / fn; fn = 1.f - EPSF; }
        }
        kh[oidx] = f2bf(kr * scale);
        if (lane == 0) y2k[h * N + n] = fn * fn;
    }
    // v transposed: vt[h][d=lane][n]
    vt[((size_t)h * 64 + lane) * N + n] = f2bf(base[1024 + h * 64 + lane]);
}

// K5: QK^T via MFMA per lower-triangular (h, 64x64 tile); epilogue computes
// hyperbolic dist + causal mask + exp -> P(bf16). 4 waves, 2x2 of 32x32.
__global__ __launch_bounds__(256, 4) void k_qkt_mfma(
        const unsigned short* __restrict__ qh, const unsigned short* __restrict__ kh,
        const float* __restrict__ x2q, const float* __restrict__ y2k,
        const float* __restrict__ c_logits, const float* __restrict__ geo_scale,
        unsigned short* __restrict__ P) {
    const int N = 512;
    int p = blockIdx.x, h = blockIdx.y;
    int qt = 0;
    while ((qt + 1) * (qt + 2) / 2 <= p) qt++;
    int kt = p - qt * (qt + 1) / 2;
    int tid = threadIdx.x, lane = tid & 63, wv = tid >> 6;
    int wr = wv >> 1, wc = wv & 1;
    int l15 = lane & 15, kb = lane >> 4;
    int qrow0 = qt * 64 + wr * 32, kcol0 = kt * 64 + wc * 32;
    const unsigned short* qb = qh + ((size_t)h * N + qrow0 + l15) * 64 + kb * 8;
    const unsigned short* kb_ = kh + ((size_t)h * N + kcol0 + l15) * 64 + kb * 8;
    f32x4 acc[2][2] = {};
    #pragma unroll
    for (int kk = 0; kk < 2; ++kk) {
        s16x8 a0 = *(const s16x8*)(qb + kk * 32);
        s16x8 a1 = *(const s16x8*)(qb + 16 * 64 + kk * 32);
        s16x8 b0 = *(const s16x8*)(kb_ + kk * 32);
        s16x8 b1 = *(const s16x8*)(kb_ + 16 * 64 + kk * 32);
        acc[0][0] = __builtin_amdgcn_mfma_f32_16x16x32_bf16(a0, b0, acc[0][0], 0, 0, 0);
        acc[0][1] = __builtin_amdgcn_mfma_f32_16x16x32_bf16(a0, b1, acc[0][1], 0, 0, 0);
        acc[1][0] = __builtin_amdgcn_mfma_f32_16x16x32_bf16(a1, b0, acc[1][0], 0, 0, 0);
        acc[1][1] = __builtin_amdgcn_mfma_f32_16x16x32_bf16(a1, b1, acc[1][1], 0, 0, 0);
    }
    float c = log1pf(expf(c_logits[h]));
    float sqc = fmaxf(sqrtf(c), EPSF);
    float gs = geo_scale[h];
    #pragma unroll
    for (int mi = 0; mi < 2; ++mi)
        #pragma unroll
        for (int r = 0; r < 4; ++r) {
            int qi = qrow0 + mi * 16 + kb * 4 + r;
            float x2 = x2q[h * N + qi];
            float b_ = 1.f - c * x2;
            #pragma unroll
            for (int ni = 0; ni < 2; ++ni) {
                int ki = kcol0 + ni * 16 + l15;
                float y2 = y2k[h * N + ki];
                float dot = acc[mi][ni][r];
                float a_ = 1.f + c * (y2 - 2.f * dot);
                float num2 = a_ * a_ * x2 + b_ * b_ * y2 - 2.f * a_ * b_ * dot;
                float den = fmaxf(1.f - 2.f * c * dot + c * c * x2 * y2, EPSF);
                float nrm = sqrtf(fmaxf(num2, 0.f)) / den;
                if (nrm >= 1.f) nrm = 1.f - EPSF;
                float arg = fminf(sqc * nrm, 1.f - EPSF);
                float s = -gs * (2.f * atanhf(arg) / sqc);
                float pe = (ki <= qi) ? expf(s) : 0.f;
                P[((size_t)(h * N + qi)) * N + ki] = f2bf(pe);
            }
        }
}

// K6: inv_l[row] = 1 / sum(P[row, causal range)). One wave per row.
__global__ void k_rowsum(const unsigned short* __restrict__ P, float* __restrict__ inv_l) {
    const int N = 512;
    int lane = threadIdx.x & 63, wave = threadIdx.x >> 6;
    int row = blockIdx.x * 4 + wave;          // row = h*N + qi
    int qi = row & (N - 1);
    int kend = ((qi >> 6) + 1) << 6;          // only causal tiles were written
    const unsigned short* pr = P + (size_t)row * N;
    float s = 0.f;
    for (int ki = lane; ki < kend; ki += 64) s += bf2f(pr[ki]);
    s = wave_reduce_sum(s);
    if (lane == 0) inv_l[row] = 1.f / s;
}

// K7: O = P @ V via MFMA; scale by inv_l; out aout(bf16)[n][h*64+d].
// Block: 64 q-rows x 64 d, 4 waves 2x2 of 32x32. Grid (8 qtiles, 8 heads).
__global__ __launch_bounds__(256, 4) void k_pv_mfma(
        const unsigned short* __restrict__ P, const unsigned short* __restrict__ vt,
        const float* __restrict__ inv_l, unsigned short* __restrict__ aout) {
    const int N = 512;
    int qt = blockIdx.x, h = blockIdx.y;
    int tid = threadIdx.x, lane = tid & 63, wv = tid >> 6;
    int wr = wv >> 1, wc = wv & 1;
    int l15 = lane & 15, kb = lane >> 4;
    int r0 = qt * 64 + wr * 32;
    int d0 = wc * 32;
    const unsigned short* Pb = P + ((size_t)(h * N + r0 + l15)) * N + kb * 8;
    const unsigned short* Vb = vt + ((size_t)(h * 64 + d0 + l15)) * N + kb * 8;
    f32x4 acc[2][2] = {};
    int kend = r0 + 32;    // causal coverage for rows r0..r0+31
    for (int k0 = 0; k0 < kend; k0 += 32) {
        s16x8 a0 = *(const s16x8*)(Pb + k0);
        s16x8 a1 = *(const s16x8*)(Pb + (size_t)16 * N + k0);
        s16x8 b0 = *(const s16x8*)(Vb + k0);
        s16x8 b1 = *(const s16x8*)(Vb + (size_t)16 * N + k0);
        acc[0][0] = __builtin_amdgcn_mfma_f32_16x16x32_bf16(a0, b0, acc[0][0], 0, 0, 0);
        acc[0][1] = __builtin_amdgcn_mfma_f32_16x16x32_bf16(a0, b1, acc[0][1], 0, 0, 0);
        acc[1][0] = __builtin_amdgcn_mfma_f32_16x16x32_bf16(a1, b0, acc[1][0], 0, 0, 0);
        acc[1][1] = __builtin_amdgcn_mfma_f32_16x16x32_bf16(a1, b1, acc[1][1], 0, 0, 0);
    }
    #pragma unroll
    for (int mi = 0; mi < 2; ++mi)
        #pragma unroll
        for (int r = 0; r < 4; ++r) {
            int qi = r0 + mi * 16 + kb * 4 + r;
            float il = inv_l[h * N + qi];
            #pragma unroll
            for (int ni = 0; ni < 2; ++ni) {
                int d = d0 + ni * 16 + l15;
                aout[(size_t)qi * 512 + h * 64 + d] = f2bf(acc[mi][ni][r] * il);
            }
        }
}

// K8: final GEMM with fp32 out (reuses k_gemm_mfma).

extern "C" void kernel_launch(void* const* d_in, const int* in_sizes, int n_in,
                              void* d_out, int out_size, void* d_ws, size_t ws_size,
                              hipStream_t stream) {
    const float* x_hyp     = (const float*)d_in[0];
    const float* freqs     = (const float*)d_in[1];
    const float* c_sphere  = (const float*)d_in[2];
    const float* w_qkv     = (const float*)d_in[3];
    const float* b_qkv     = (const float*)d_in[4];
    const float* w_out     = (const float*)d_in[5];
    const float* b_out     = (const float*)d_in[6];
    const float* c_logits  = (const float*)d_in[7];
    const float* geo_scale = (const float*)d_in[8];
    float* out = (float*)d_out;

    const int N = 512, D = 512, H = 8;
    char* base = (char*)d_ws;
    unsigned short* x_tan16 = (unsigned short*)base;                 base += 512 * 1024;
    float*          qkv     = (float*)base;                          base += 3 * 1024 * 1024;
    unsigned short* qh16    = (unsigned short*)base;                 base += 512 * 1024;
    unsigned short* kh16    = (unsigned short*)base;                 base += 512 * 1024;
    unsigned short* vt16    = (unsigned short*)base;                 base += 512 * 1024;
    float*          x2q     = (float*)base;                          base += 16 * 1024;
    float*          y2k     = (float*)base;                          base += 16 * 1024;
    float*          inv_l   = (float*)base;                          base += 16 * 1024;
    unsigned short* aout16  = (unsigned short*)base;                 base += 512 * 1024;
    unsigned short* P16     = (unsigned short*)base;                 base += 4 * 1024 * 1024;
    unsigned short* wqkvT   = (unsigned short*)base;                 base += 1536 * 512 * 2;
    unsigned short* woutT   = (unsigned short*)base;                 base += 512 * 512 * 2;

    k_logmap<<<N, 256, 0, stream>>>(x_hyp, c_sphere, x_tan16, N, D);
    k_transpose_bf16<<<dim3(1536 / 64, D / 64), 256, 0, stream>>>(w_qkv, wqkvT, D, 1536);
    k_transpose_bf16<<<dim3(D / 64, D / 64), 256, 0, stream>>>(w_out, woutT, D, D);
    // qkv = x_tan @ w_qkv + b_qkv : M=512, N=1536, K=512 -> 768 waves -> 192 blocks
    k_gemm_mfma<<<(512 / 32) * (1536 / 32) / 4, 256, 0, stream>>>(
        x_tan16, wqkvT, b_qkv, qkv, N, 1536, D);
    k_rope_expmap<<<(H * N) / 4, 256, 0, stream>>>(qkv, freqs, c_logits, qh16, kh16, vt16, x2q, y2k);
    k_qkt_mfma<<<dim3(36, H), 256, 0, stream>>>(qh16, kh16, x2q, y2k, c_logits, geo_scale, P16);
    k_rowsum<<<(H * N) / 4, 256, 0, stream>>>(P16, inv_l);
    k_pv_mfma<<<dim3(8, H), 256, 0, stream>>>(P16, vt16, inv_l, aout16);
    // out = aout @ w_out + b_out : M=512, N=512, K=512 -> 256 waves -> 64 blocks
    k_gemm_mfma<<<(512 / 32) * (512 / 32) / 4, 256, 0, stream>>>(
        aout16, woutT, b_out, out, N, D, D);
}